// Round 2
// baseline (1620.238 us; speedup 1.0000x reference)
//
#include <hip/hip_runtime.h>
#include <math.h>

#define TZ 8
#define TH 96
#define TW 192
#define C 192
#define NHEADS 6
#define HDIM 32
#define LW 144
#define NWIN 1024
#define NTOK 147456
#define NPOS 3312
#define QSCALE 0.17677669529663687f

typedef unsigned short u16;
typedef __attribute__((ext_vector_type(8))) short bf8_t;
typedef __attribute__((ext_vector_type(4))) short bf4_t;
typedef __attribute__((ext_vector_type(4))) unsigned short us4_t;
typedef __attribute__((ext_vector_type(4))) float f4_t;

__device__ __forceinline__ float bf2f(u16 u) {
    union { unsigned int i; float f; } c; c.i = ((unsigned int)u) << 16; return c.f;
}
__device__ __forceinline__ u16 f2bf(float f) {
    union { float f; unsigned int i; } c; c.f = f;
    unsigned int x = c.i;
    x += 0x7fffu + ((x >> 16) & 1u);   // RNE
    return (u16)(x >> 16);
}

// windowed row -> token (with optional roll). Row r in [0, NTOK).
__device__ __forceinline__ int win_row_to_token(int r, int roll) {
    int wi = r / LW, l = r % LW;
    int nz = wi >> 8, nh = (wi >> 4) & 15, nw = wi & 15;
    int iz = l / 72, rr = l % 72, ih = rr / 12, iw = rr % 12;
    int z = nz * 2 + iz, h = nh * 6 + ih, w = nw * 12 + iw;
    if (roll) {
        z = (z + 1) & 7;
        h += 3; if (h >= TH) h -= TH;
        w += 6; if (w >= TW) w -= TW;
    }
    return (z * TH + h) * TW + w;
}

// ---------------- fused LN (+gather/roll) -> bf16, one wave per row ----------------
__global__ __launch_bounds__(256) void ln_kernel(
    const float* __restrict__ x, const float* __restrict__ g,
    const float* __restrict__ b, u16* __restrict__ xnc,
    int row0, int windowed, int roll)
{
    int wave = threadIdx.x >> 6;
    int lane = threadIdx.x & 63;
    int dl = blockIdx.x * 4 + wave;
    int d = row0 + dl;
    int src = windowed ? win_row_to_token(d, roll) : d;
    const float* xr = x + (size_t)src * C;
    float v0 = xr[lane], v1 = xr[lane + 64], v2 = xr[lane + 128];
    float s = v0 + v1 + v2;
    float sq = v0 * v0 + v1 * v1 + v2 * v2;
    #pragma unroll
    for (int off = 32; off > 0; off >>= 1) {
        s  += __shfl_xor(s, off, 64);
        sq += __shfl_xor(sq, off, 64);
    }
    float mean = s * (1.0f / 192.0f);
    float var  = sq * (1.0f / 192.0f) - mean * mean;
    float rstd = rsqrtf(var + 1e-5f);
    u16* orow = xnc + (size_t)dl * C;
    orow[lane]       = f2bf((v0 - mean) * rstd * g[lane]       + b[lane]);
    orow[lane + 64]  = f2bf((v1 - mean) * rstd * g[lane + 64]  + b[lane + 64]);
    orow[lane + 128] = f2bf((v2 - mean) * rstd * g[lane + 128] + b[lane + 128]);
}

// ---------------- weight transpose + bf16 convert: WT[n][k] = W[k][n] ----------------
__global__ __launch_bounds__(256) void tconv_kernel(
    const float* __restrict__ W, u16* __restrict__ WT, int K, int N)
{
    int idx = blockIdx.x * 256 + threadIdx.x;
    if (idx >= N * K) return;
    int n = idx / K, k = idx % K;
    WT[idx] = f2bf(W[(size_t)k * N + n]);
}

// ---------------- bias table materialization: biasf[wt][head][i][j] (bf16) ----------------
__global__ __launch_bounds__(256) void biasmat_kernel(
    const float* __restrict__ btab, const int* __restrict__ pidx,
    u16* __restrict__ biasf)
{
    int wt = blockIdx.x, head = blockIdx.y;
    size_t obase = ((size_t)wt * 6 + head) * (LW * LW);
    for (int idx = threadIdx.x; idx < LW * LW; idx += 256) {
        int p = pidx[idx];
        biasf[obase + idx] = f2bf(btab[((size_t)p * 64 + wt) * 6 + head]);
    }
}

// ---------------- bf16 MFMA GEMM: tile 128x64, BK=64, 4 waves (2x2) ----------------
template <int MODE>
__global__ __launch_bounds__(256) void mm_kernel(
    const u16* __restrict__ A, const u16* __restrict__ BT,
    const float* __restrict__ bias, void* __restrict__ Cvoid,
    int N, int K, int row0, int roll)
{
    __shared__ alignas(16) u16 As[128 * 72];
    __shared__ alignas(16) u16 Bs[64 * 72];
    int tid = threadIdx.x;
    int mb = blockIdx.y * 128, nb = blockIdx.x * 64;
    int wave = tid >> 6, lane = tid & 63;
    int mh = wave >> 1, nh = wave & 1;
    int lr = lane & 15, g = lane >> 4;

    f4_t acc[4][2];
    #pragma unroll
    for (int mi = 0; mi < 4; mi++)
        #pragma unroll
        for (int ni = 0; ni < 2; ni++)
            acc[mi][ni] = (f4_t){0.f, 0.f, 0.f, 0.f};

    for (int k0 = 0; k0 < K; k0 += 64) {
        #pragma unroll
        for (int it = 0; it < 4; it++) {
            int idx = it * 256 + tid;
            int r = idx >> 3, kc = idx & 7;
            *(bf8_t*)&As[r * 72 + kc * 8] =
                *(const bf8_t*)&A[(size_t)(mb + r) * K + k0 + kc * 8];
        }
        #pragma unroll
        for (int it = 0; it < 2; it++) {
            int idx = it * 256 + tid;
            int r = idx >> 3, kc = idx & 7;
            *(bf8_t*)&Bs[r * 72 + kc * 8] =
                *(const bf8_t*)&BT[(size_t)(nb + r) * K + k0 + kc * 8];
        }
        __syncthreads();
        #pragma unroll
        for (int ks = 0; ks < 2; ks++) {
            bf8_t bfr[2];
            #pragma unroll
            for (int ni = 0; ni < 2; ni++)
                bfr[ni] = *(const bf8_t*)&Bs[(nh * 32 + ni * 16 + lr) * 72 + ks * 32 + g * 8];
            #pragma unroll
            for (int mi = 0; mi < 4; mi++) {
                bf8_t afr = *(const bf8_t*)&As[(mh * 64 + mi * 16 + lr) * 72 + ks * 32 + g * 8];
                #pragma unroll
                for (int ni = 0; ni < 2; ni++)
                    acc[mi][ni] = __builtin_amdgcn_mfma_f32_16x16x32_bf16(
                        afr, bfr[ni], acc[mi][ni], 0, 0, 0);
            }
        }
        __syncthreads();
    }

    #pragma unroll
    for (int mi = 0; mi < 4; mi++) {
        int rbase = mb + mh * 64 + mi * 16 + g * 4;
        int tok[4];
        if (MODE == 1) {
            #pragma unroll
            for (int r = 0; r < 4; r++)
                tok[r] = win_row_to_token(row0 + rbase + r, roll);
        }
        #pragma unroll
        for (int ni = 0; ni < 2; ni++) {
            int col = nb + nh * 32 + ni * 16 + lr;
            float bb = bias[col];
            #pragma unroll
            for (int r = 0; r < 4; r++) {
                float v = acc[mi][ni][r] + bb;
                if (MODE == 0) {
                    if (col < 192) v *= QSCALE;
                    ((u16*)Cvoid)[(size_t)(rbase + r) * 576 + col] = f2bf(v);
                } else if (MODE == 1) {
                    ((float*)Cvoid)[(size_t)tok[r] * C + col] += v;
                } else if (MODE == 2) {
                    v = 0.5f * v * (1.0f + erff(v * 0.70710678118654752f));
                    ((u16*)Cvoid)[(size_t)(rbase + r) * 768 + col] = f2bf(v);
                } else {
                    ((float*)Cvoid)[(size_t)(row0 + rbase + r) * C + col] += v;
                }
            }
        }
    }
}

// ---------------- MFMA attention, swapped-QK in-register softmax ----------------
// S^T = mfma(K,Q): lane(g,lr) holds S[j=jt*16+g*4+r][i=it*16+lr].
// Softmax j-reduction: in-lane over 36 vals + shfl_xor(16,32).
// PV: P stays in registers as the B-operand; V^T from LDS is the A-operand.
// Two 16-wide j-tiles packed per 16x16x32 MFMA (k slots g*8+m <-> j=jt*16+g*4+m).
__global__ __launch_bounds__(192, 4) void attn_kernel(
    const u16* __restrict__ qkvb, const u16* __restrict__ biasf,
    u16* __restrict__ attnb, int win0, int roll)
{
    __shared__ alignas(16) u16 Qs[144 * 40];          // 11520 B
    __shared__ alignas(16) u16 Ks[144 * 40];          // 11520 B
    __shared__ alignas(16) u16 Vt[32 * 148];          //  9472 B  (V^T, stride 148)
    __shared__ unsigned char region8[144];            //   144 B  -> total ~32.7 KB

    int wl = blockIdx.x, head = blockIdx.y;
    int wi = win0 + wl, wt = wi & 63;
    int tid = threadIdx.x;

    const u16* base = qkvb + (size_t)wl * LW * 576;
    // vectorized staging: 144 rows x 32 d = 576 bf8 chunks per matrix, 3 per thread
    for (int c = tid; c < 576; c += 192) {
        int l = c >> 2, d8 = (c & 3) << 3;
        const u16* row = base + (size_t)l * 576 + head * 32;
        *(bf8_t*)&Qs[l * 40 + d8] = *(const bf8_t*)&row[d8];
        *(bf8_t*)&Ks[l * 40 + d8] = *(const bf8_t*)&row[192 + d8];
        bf8_t v8 = *(const bf8_t*)&row[384 + d8];
        #pragma unroll
        for (int m = 0; m < 8; m++)
            Vt[(d8 + m) * 148 + l] = (u16)v8[m];
    }
    if (tid < 144) {
        int nz = wi >> 8, nh = (wi >> 4) & 15, nw = wi & 15;
        int iz = tid / 72, rr = tid % 72, ih = rr / 12, iw = rr % 12;
        int z = nz * 2 + iz, h = nh * 6 + ih, w = nw * 12 + iw;
        int rz = (z < 6) ? 0 : ((z < 7) ? 1 : 2);
        int rh = (h < 90) ? 0 : ((h < 93) ? 1 : 2);
        int rw2 = (w < 180) ? 0 : ((w < 186) ? 1 : 2);
        region8[tid] = (unsigned char)(rz * 9 + rh * 3 + rw2);
    }
    __syncthreads();

    int wave = tid >> 6, lane = tid & 63;
    int lr = lane & 15, g = lane >> 4;
    int jb = g << 2;                 // j sub-offset per g-group
    const f4_t z4 = {0.f, 0.f, 0.f, 0.f};

    for (int itl = 0; itl < 3; itl++) {
        int it = wave * 3 + itl;
        int i_row = it * 16 + lr;
        bf8_t qf = *(const bf8_t*)&Qs[i_row * 40 + (g << 3)];
        f4_t s[9];
        #pragma unroll
        for (int jt = 0; jt < 9; jt++) {
            bf8_t kf = *(const bf8_t*)&Ks[(jt * 16 + lr) * 40 + (g << 3)];
            s[jt] = __builtin_amdgcn_mfma_f32_16x16x32_bf16(kf, qf, z4, 0, 0, 0);
        }

        const u16* bb = biasf + ((size_t)(wt * 6 + head) * LW + i_row) * LW;
        unsigned int ri = region8[i_row];
        float m4[4] = {-1e30f, -1e30f, -1e30f, -1e30f};
        #pragma unroll
        for (int jt = 0; jt < 9; jt++) {
            us4_t b4 = *(const us4_t*)&bb[jt * 16 + jb];
            unsigned int rj = 0;
            if (roll) rj = *(const unsigned int*)&region8[jt * 16 + jb];
            #pragma unroll
            for (int r = 0; r < 4; r++) {
                float v = s[jt][r] + bf2f(b4[r]);
                if (roll && (((rj >> (8 * r)) & 255u) != ri)) v -= 100.0f;
                s[jt][r] = v;
                m4[r] = fmaxf(m4[r], v);
            }
        }
        float m = fmaxf(fmaxf(m4[0], m4[1]), fmaxf(m4[2], m4[3]));
        m = fmaxf(m, __shfl_xor(m, 16, 64));
        m = fmaxf(m, __shfl_xor(m, 32, 64));

        float l4[4] = {0.f, 0.f, 0.f, 0.f};
        #pragma unroll
        for (int jt = 0; jt < 9; jt++)
            #pragma unroll
            for (int r = 0; r < 4; r++) {
                float p = __expf(s[jt][r] - m);
                s[jt][r] = p;
                l4[r] += p;
            }
        float lsum = (l4[0] + l4[1]) + (l4[2] + l4[3]);
        lsum += __shfl_xor(lsum, 16, 64);
        lsum += __shfl_xor(lsum, 32, 64);
        float inv = 1.0f / lsum;

        // pack P (bf16) into B-operand fragments: pair jt tiles (2t, 2t+1)
        bf8_t pfrag[5];
        #pragma unroll
        for (int t = 0; t < 4; t++)
            #pragma unroll
            for (int m2 = 0; m2 < 4; m2++) {
                pfrag[t][m2]     = (short)f2bf(s[2 * t][m2] * inv);
                pfrag[t][4 + m2] = (short)f2bf(s[2 * t + 1][m2] * inv);
            }
        #pragma unroll
        for (int m2 = 0; m2 < 4; m2++) {
            pfrag[4][m2]     = (short)f2bf(s[8][m2] * inv);
            pfrag[4][4 + m2] = 0;
        }

        #pragma unroll
        for (int dt = 0; dt < 2; dt++) {
            const u16* vrow = &Vt[(dt * 16 + lr) * 148];
            f4_t acc = z4;
            #pragma unroll
            for (int t = 0; t < 5; t++) {
                bf4_t va = *(const bf4_t*)&vrow[t * 32 + jb];
                bf8_t af;
                #pragma unroll
                for (int m2 = 0; m2 < 4; m2++) af[m2] = va[m2];
                if (t < 4) {
                    bf4_t vb = *(const bf4_t*)&vrow[t * 32 + 16 + jb];
                    #pragma unroll
                    for (int m2 = 0; m2 < 4; m2++) af[4 + m2] = vb[m2];
                } else {
                    #pragma unroll
                    for (int m2 = 0; m2 < 4; m2++) af[4 + m2] = 0;
                }
                acc = __builtin_amdgcn_mfma_f32_16x16x32_bf16(af, pfrag[t], acc, 0, 0, 0);
            }
            // lane holds O[i=i_row][d = dt*16 + g*4 + r] -> one 8B store
            us4_t o;
            #pragma unroll
            for (int r = 0; r < 4; r++) o[r] = f2bf(acc[r]);
            *(us4_t*)&attnb[((size_t)wl * LW + i_row) * 192 + head * 32 + dt * 16 + jb] = o;
        }
    }
}

extern "C" void kernel_launch(void* const* d_in, const int* in_sizes, int n_in,
                              void* d_out, int out_size, void* d_ws, size_t ws_size,
                              hipStream_t stream)
{
    (void)in_sizes; (void)n_in; (void)out_size; (void)ws_size;
    const float* x_in   = (const float*)d_in[0];
    const float* qkv_w  = (const float*)d_in[1];
    const float* qkv_b  = (const float*)d_in[2];
    const float* proj_w = (const float*)d_in[3];
    const float* proj_b = (const float*)d_in[4];
    const float* btab   = (const float*)d_in[5];
    const float* n1g    = (const float*)d_in[6];
    const float* n1b    = (const float*)d_in[7];
    const float* n2g    = (const float*)d_in[8];
    const float* n2b    = (const float*)d_in[9];
    const float* w1     = (const float*)d_in[10];
    const float* b1     = (const float*)d_in[11];
    const float* w2     = (const float*)d_in[12];
    const float* b2     = (const float*)d_in[13];
    const int*   pidx   = (const int*)d_in[14];

    float* x   = (float*)d_out;
    u16* biasf = (u16*)d_ws;
    u16* wT    = biasf + (size_t)64 * 6 * LW * LW;
    u16* xnc   = wT + 884736;
    u16* qkvb  = xnc + (size_t)NTOK * C;
    u16* attnb = qkvb + (size_t)NTOK * 576;
    u16* hidb  = qkvb;                                   // NTOK*768 overlaps qkvb+attnb

    const size_t WBLK = 442368;
    const size_t OQKV = 0, OPROJ = 110592, OW1 = 147456, OW2 = 294912;

    hipMemcpyAsync(x, x_in, (size_t)NTOK * C * sizeof(float),
                   hipMemcpyDeviceToDevice, stream);

    for (int blk = 0; blk < 2; blk++) {
        u16* wb = wT + blk * WBLK;
        tconv_kernel<<<(576 * 192 + 255) / 256, 256, 0, stream>>>(
            qkv_w + (size_t)blk * C * 576, wb + OQKV, C, 576);
        tconv_kernel<<<(192 * 192 + 255) / 256, 256, 0, stream>>>(
            proj_w + (size_t)blk * C * C, wb + OPROJ, C, 192);
        tconv_kernel<<<(768 * 192 + 255) / 256, 256, 0, stream>>>(
            w1 + (size_t)blk * C * 768, wb + OW1, C, 768);
        tconv_kernel<<<(192 * 768 + 255) / 256, 256, 0, stream>>>(
            w2 + (size_t)blk * 768 * C, wb + OW2, 768, 192);
    }

    for (int blk = 0; blk < 2; blk++) {
        int roll = blk & 1;
        u16* wb = wT + blk * WBLK;
        biasmat_kernel<<<dim3(64, 6), 256, 0, stream>>>(
            btab + (size_t)blk * NPOS * 64 * 6, pidx, biasf);
        ln_kernel<<<NTOK / 4, 256, 0, stream>>>(
            x, n1g + blk * C, n1b + blk * C, xnc, 0, 1, roll);
        mm_kernel<0><<<dim3(9, NTOK / 128), 256, 0, stream>>>(
            xnc, wb + OQKV, qkv_b + blk * 576, qkvb, 576, C, 0, roll);
        attn_kernel<<<dim3(NWIN, NHEADS), 192, 0, stream>>>(
            qkvb, biasf, attnb, 0, roll);
        mm_kernel<1><<<dim3(3, NTOK / 128), 256, 0, stream>>>(
            attnb, wb + OPROJ, proj_b + blk * C, x, 192, C, 0, roll);
        ln_kernel<<<NTOK / 4, 256, 0, stream>>>(
            x, n2g + blk * C, n2b + blk * C, xnc, 0, 0, 0);
        mm_kernel<2><<<dim3(12, NTOK / 128), 256, 0, stream>>>(
            xnc, wb + OW1, b1 + blk * 768, hidb, 768, C, 0, 0);
        mm_kernel<3><<<dim3(3, NTOK / 128), 256, 0, stream>>>(
            hidb, wb + OW2, b2 + blk * C, x, 192, 768, 0, 0);
    }
}

// Round 4
// 1593.654 us; speedup vs baseline: 1.0167x; 1.0167x over previous
//
#include <hip/hip_runtime.h>
#include <math.h>

#define TZ 8
#define TH 96
#define TW 192
#define C 192
#define NHEADS 6
#define HDIM 32
#define LW 144
#define NWIN 1024
#define NTOK 147456
#define NPOS 3312
#define QSCALE 0.17677669529663687f
#define VHS 4772                          // per-head V^T block stride (u16), mult of 4

typedef unsigned short u16;
typedef __attribute__((ext_vector_type(8))) short bf8_t;
typedef __attribute__((ext_vector_type(4))) short bf4_t;
typedef __attribute__((ext_vector_type(4))) unsigned short us4_t;
typedef __attribute__((ext_vector_type(4))) float f4_t;

__device__ __forceinline__ float bf2f(u16 u) {
    union { unsigned int i; float f; } c; c.i = ((unsigned int)u) << 16; return c.f;
}
__device__ __forceinline__ u16 f2bf(float f) {
    union { float f; unsigned int i; } c; c.f = f;
    unsigned int x = c.i;
    x += 0x7fffu + ((x >> 16) & 1u);   // RNE
    return (u16)(x >> 16);
}

// windowed row -> token (with optional roll). Row r in [0, NTOK).
__device__ __forceinline__ int win_row_to_token(int r, int roll) {
    int wi = r / LW, l = r % LW;
    int nz = wi >> 8, nh = (wi >> 4) & 15, nw = wi & 15;
    int iz = l / 72, rr = l % 72, ih = rr / 12, iw = rr % 12;
    int z = nz * 2 + iz, h = nh * 6 + ih, w = nw * 12 + iw;
    if (roll) {
        z = (z + 1) & 7;
        h += 3; if (h >= TH) h -= TH;
        w += 6; if (w >= TW) w -= TW;
    }
    return (z * TH + h) * TW + w;
}

// ---------------- fused LN (+gather/roll) -> bf16, one wave per row ----------------
__global__ __launch_bounds__(256) void ln_kernel(
    const float* __restrict__ x, const float* __restrict__ g,
    const float* __restrict__ b, u16* __restrict__ xnc,
    int row0, int windowed, int roll)
{
    int wave = threadIdx.x >> 6;
    int lane = threadIdx.x & 63;
    int dl = blockIdx.x * 4 + wave;
    int d = row0 + dl;
    int src = windowed ? win_row_to_token(d, roll) : d;
    const float* xr = x + (size_t)src * C;
    float v0 = xr[lane], v1 = xr[lane + 64], v2 = xr[lane + 128];
    float s = v0 + v1 + v2;
    float sq = v0 * v0 + v1 * v1 + v2 * v2;
    #pragma unroll
    for (int off = 32; off > 0; off >>= 1) {
        s  += __shfl_xor(s, off, 64);
        sq += __shfl_xor(sq, off, 64);
    }
    float mean = s * (1.0f / 192.0f);
    float var  = sq * (1.0f / 192.0f) - mean * mean;
    float rstd = rsqrtf(var + 1e-5f);
    u16* orow = xnc + (size_t)dl * C;
    orow[lane]       = f2bf((v0 - mean) * rstd * g[lane]       + b[lane]);
    orow[lane + 64]  = f2bf((v1 - mean) * rstd * g[lane + 64]  + b[lane + 64]);
    orow[lane + 128] = f2bf((v2 - mean) * rstd * g[lane + 128] + b[lane + 128]);
}

// ---------------- weight transpose + bf16 convert: WT[n][k] = W[k][n] ----------------
__global__ __launch_bounds__(256) void tconv_kernel(
    const float* __restrict__ W, u16* __restrict__ WT, int K, int N)
{
    int idx = blockIdx.x * 256 + threadIdx.x;
    if (idx >= N * K) return;
    int n = idx / K, k = idx % K;
    WT[idx] = f2bf(W[(size_t)k * N + n]);
}

// ---------------- bias table: biasf[wt][head][i][j] (bf16) ----------------
__global__ __launch_bounds__(256) void biasmat_kernel(
    const float* __restrict__ btab, const int* __restrict__ pidx,
    u16* __restrict__ biasf)
{
    int wt = blockIdx.x, head = blockIdx.y;
    size_t obase = ((size_t)wt * 6 + head) * (LW * LW);
    for (int idx = threadIdx.x; idx < LW * LW; idx += 256) {
        int p = pidx[idx];
        biasf[obase + idx] = f2bf(btab[((size_t)p * 64 + wt) * 6 + head]);
    }
}

// ---------------- bf16 MFMA GEMM: tile 128x64, BK=64, 4 waves (2x2) ----------------
template <int MODE>
__global__ __launch_bounds__(256) void mm_kernel(
    const u16* __restrict__ A, const u16* __restrict__ BT,
    const float* __restrict__ bias, void* __restrict__ Cvoid,
    int N, int K, int row0, int roll)
{
    __shared__ alignas(16) u16 As[128 * 72];
    __shared__ alignas(16) u16 Bs[64 * 72];
    int tid = threadIdx.x;
    int mb = blockIdx.y * 128, nb = blockIdx.x * 64;
    int wave = tid >> 6, lane = tid & 63;
    int mh = wave >> 1, nh = wave & 1;
    int lr = lane & 15, g = lane >> 4;

    f4_t acc[4][2];
    #pragma unroll
    for (int mi = 0; mi < 4; mi++)
        #pragma unroll
        for (int ni = 0; ni < 2; ni++)
            acc[mi][ni] = (f4_t){0.f, 0.f, 0.f, 0.f};

    for (int k0 = 0; k0 < K; k0 += 64) {
        #pragma unroll
        for (int it = 0; it < 4; it++) {
            int idx = it * 256 + tid;
            int r = idx >> 3, kc = idx & 7;
            *(bf8_t*)&As[r * 72 + kc * 8] =
                *(const bf8_t*)&A[(size_t)(mb + r) * K + k0 + kc * 8];
        }
        #pragma unroll
        for (int it = 0; it < 2; it++) {
            int idx = it * 256 + tid;
            int r = idx >> 3, kc = idx & 7;
            *(bf8_t*)&Bs[r * 72 + kc * 8] =
                *(const bf8_t*)&BT[(size_t)(nb + r) * K + k0 + kc * 8];
        }
        __syncthreads();
        #pragma unroll
        for (int ks = 0; ks < 2; ks++) {
            bf8_t bfr[2];
            #pragma unroll
            for (int ni = 0; ni < 2; ni++)
                bfr[ni] = *(const bf8_t*)&Bs[(nh * 32 + ni * 16 + lr) * 72 + ks * 32 + g * 8];
            #pragma unroll
            for (int mi = 0; mi < 4; mi++) {
                bf8_t afr = *(const bf8_t*)&As[(mh * 64 + mi * 16 + lr) * 72 + ks * 32 + g * 8];
                #pragma unroll
                for (int ni = 0; ni < 2; ni++)
                    acc[mi][ni] = __builtin_amdgcn_mfma_f32_16x16x32_bf16(
                        afr, bfr[ni], acc[mi][ni], 0, 0, 0);
            }
        }
        __syncthreads();
    }

    #pragma unroll
    for (int mi = 0; mi < 4; mi++) {
        int rbase = mb + mh * 64 + mi * 16 + g * 4;
        int tok[4];
        if (MODE == 1) {
            #pragma unroll
            for (int r = 0; r < 4; r++)
                tok[r] = win_row_to_token(row0 + rbase + r, roll);
        }
        #pragma unroll
        for (int ni = 0; ni < 2; ni++) {
            int col = nb + nh * 32 + ni * 16 + lr;
            float bb = bias[col];
            #pragma unroll
            for (int r = 0; r < 4; r++) {
                float v = acc[mi][ni][r] + bb;
                if (MODE == 0) {
                    if (col < 192) v *= QSCALE;
                    ((u16*)Cvoid)[(size_t)(rbase + r) * 576 + col] = f2bf(v);
                } else if (MODE == 1) {
                    ((float*)Cvoid)[(size_t)tok[r] * C + col] += v;
                } else if (MODE == 2) {
                    v = 0.5f * v * (1.0f + erff(v * 0.70710678118654752f));
                    ((u16*)Cvoid)[(size_t)(rbase + r) * 768 + col] = f2bf(v);
                } else {
                    ((float*)Cvoid)[(size_t)(row0 + rbase + r) * C + col] += v;
                }
            }
        }
    }
}

// ---------------- MFMA attention v4: one block = one window, wave = head ----------
// Structure of v3 (verified index-by-index against round-2 layout), numerics of
// round-2 (max-subtract, natural exp, f2bf packing, P normalized before PV).
// S^T = mfma(K,Q): lane(g,lr) holds S[j=jt*16+g*4+r][i=it*16+lr].
template <int ROLL>
__global__ __launch_bounds__(384, 3) void attn_kernel(
    const u16* __restrict__ qkvb, const u16* __restrict__ biasf,
    u16* __restrict__ attnb)
{
    __shared__ alignas(16) u16 Vt[6 * VHS];           // 57264 B
    __shared__ unsigned char region8[148];

    int wl = blockIdx.x;
    int wt = wl & 63;
    int tid = threadIdx.x;
    const u16* base = qkvb + (size_t)wl * LW * 576;

    // stage V^T for all heads: 144 rows x 24 16B-chunks = 3456 chunks, 9/thread
    #pragma unroll
    for (int st = 0; st < 9; st++) {
        int idx = st * 384 + tid;
        int l = idx / 24, c = idx % 24;
        int h = c >> 2, dloc = (c & 3) << 3;
        bf8_t v8 = *(const bf8_t*)&base[(size_t)l * 576 + 384 + c * 8];
        u16* dst = &Vt[h * VHS + dloc * 148 + l];
        #pragma unroll
        for (int m = 0; m < 8; m++)
            dst[m * 148] = (u16)v8[m];
    }
    bool doMask = false;
    if (ROLL) {
        int nz = wl >> 8, nh = (wl >> 4) & 15, nw = wl & 15;
        doMask = (nz == 3) || (nh == 15) || (nw == 15);
        if (tid < 144) {
            int iz = tid / 72, rr = tid % 72, ih = rr / 12, iw = rr % 12;
            int z = nz * 2 + iz, h = nh * 6 + ih, w = nw * 12 + iw;
            int rz = (z < 6) ? 0 : ((z < 7) ? 1 : 2);
            int rh = (h < 90) ? 0 : ((h < 93) ? 1 : 2);
            int rw2 = (w < 180) ? 0 : ((w < 186) ? 1 : 2);
            region8[tid] = (unsigned char)(rz * 9 + rh * 3 + rw2);
        }
    }
    __syncthreads();

    int head = tid >> 6, lane = tid & 63;
    int lr = lane & 15, g = lane >> 4;
    int jb = g << 2;

    // K fragments resident in registers (reused across all 9 i-tiles)
    const u16* kbase = base + 192 + head * 32 + g * 8;
    bf8_t kf[9];
    #pragma unroll
    for (int jt = 0; jt < 9; jt++)
        kf[jt] = *(const bf8_t*)&kbase[(size_t)(jt * 16 + lr) * 576];

    const u16* qbase = base + head * 32 + g * 8;
    const u16* vhead = &Vt[head * VHS];
    const u16* bbb = biasf + (size_t)(wt * 6 + head) * LW * LW + jb;
    u16* obase = attnb + (size_t)wl * LW * 192 + head * 32 + jb;

    const f4_t z4 = {0.f, 0.f, 0.f, 0.f};
    bf8_t qf = *(const bf8_t*)&qbase[(size_t)lr * 576];

    for (int it = 0; it < 9; it++) {
        int i_row = it * 16 + lr;
        // bias prefetch (8B per jt)
        us4_t barr[9];
        const u16* bb = bbb + (size_t)i_row * LW;
        #pragma unroll
        for (int jt = 0; jt < 9; jt++) barr[jt] = *(const us4_t*)&bb[jt * 16];

        f4_t s[9];
        #pragma unroll
        for (int jt = 0; jt < 9; jt++)
            s[jt] = __builtin_amdgcn_mfma_f32_16x16x32_bf16(kf[jt], qf, z4, 0, 0, 0);

        bf8_t qf_n = qf;
        if (it < 8) qf_n = *(const bf8_t*)&qbase[(size_t)(i_row + 16) * 576];

        // + bias, + mask, running max (round-2 numerics)
        float m4[4] = {-1e30f, -1e30f, -1e30f, -1e30f};
        if (ROLL && doMask) {
            unsigned int ri = region8[i_row];
            #pragma unroll
            for (int jt = 0; jt < 9; jt++) {
                unsigned int rj = *(const unsigned int*)&region8[jt * 16 + jb];
                #pragma unroll
                for (int r = 0; r < 4; r++) {
                    float v = s[jt][r] + bf2f(barr[jt][r]);
                    if (((rj >> (8 * r)) & 255u) != ri) v -= 100.0f;
                    s[jt][r] = v;
                    m4[r] = fmaxf(m4[r], v);
                }
            }
        } else {
            #pragma unroll
            for (int jt = 0; jt < 9; jt++)
                #pragma unroll
                for (int r = 0; r < 4; r++) {
                    float v = s[jt][r] + bf2f(barr[jt][r]);
                    s[jt][r] = v;
                    m4[r] = fmaxf(m4[r], v);
                }
        }
        float m = fmaxf(fmaxf(m4[0], m4[1]), fmaxf(m4[2], m4[3]));
        m = fmaxf(m, __shfl_xor(m, 16, 64));
        m = fmaxf(m, __shfl_xor(m, 32, 64));

        float l4[4] = {0.f, 0.f, 0.f, 0.f};
        #pragma unroll
        for (int jt = 0; jt < 9; jt++)
            #pragma unroll
            for (int r = 0; r < 4; r++) {
                float p = __expf(s[jt][r] - m);
                s[jt][r] = p;
                l4[r] += p;
            }
        float lsum = (l4[0] + l4[1]) + (l4[2] + l4[3]);
        lsum += __shfl_xor(lsum, 16, 64);
        lsum += __shfl_xor(lsum, 32, 64);
        float inv = 1.0f / lsum;

        // pack normalized P (bf16) into B-operand fragments (pair jt tiles 2t,2t+1)
        bf8_t pfrag[5];
        #pragma unroll
        for (int t = 0; t < 4; t++)
            #pragma unroll
            for (int m2 = 0; m2 < 4; m2++) {
                pfrag[t][m2]     = (short)f2bf(s[2 * t][m2] * inv);
                pfrag[t][4 + m2] = (short)f2bf(s[2 * t + 1][m2] * inv);
            }
        #pragma unroll
        for (int m2 = 0; m2 < 4; m2++) {
            pfrag[4][m2]     = (short)f2bf(s[8][m2] * inv);
            pfrag[4][4 + m2] = 0;
        }

        #pragma unroll
        for (int dt = 0; dt < 2; dt++) {
            const u16* vrow = vhead + (dt * 16 + lr) * 148;
            f4_t acc = z4;
            #pragma unroll
            for (int t = 0; t < 5; t++) {
                bf4_t va = *(const bf4_t*)&vrow[t * 32 + jb];
                bf8_t af;
                #pragma unroll
                for (int m2 = 0; m2 < 4; m2++) af[m2] = va[m2];
                if (t < 4) {
                    bf4_t vb = *(const bf4_t*)&vrow[t * 32 + 16 + jb];
                    #pragma unroll
                    for (int m2 = 0; m2 < 4; m2++) af[4 + m2] = vb[m2];
                } else {
                    #pragma unroll
                    for (int m2 = 0; m2 < 4; m2++) af[4 + m2] = 0;
                }
                acc = __builtin_amdgcn_mfma_f32_16x16x32_bf16(af, pfrag[t], acc, 0, 0, 0);
            }
            us4_t o;
            #pragma unroll
            for (int r = 0; r < 4; r++) o[r] = f2bf(acc[r]);
            *(us4_t*)&obase[((size_t)i_row) * 192 + dt * 16] = o;
        }
        qf = qf_n;
    }
}

extern "C" void kernel_launch(void* const* d_in, const int* in_sizes, int n_in,
                              void* d_out, int out_size, void* d_ws, size_t ws_size,
                              hipStream_t stream)
{
    (void)in_sizes; (void)n_in; (void)out_size; (void)ws_size;
    const float* x_in   = (const float*)d_in[0];
    const float* qkv_w  = (const float*)d_in[1];
    const float* qkv_b  = (const float*)d_in[2];
    const float* proj_w = (const float*)d_in[3];
    const float* proj_b = (const float*)d_in[4];
    const float* btab   = (const float*)d_in[5];
    const float* n1g    = (const float*)d_in[6];
    const float* n1b    = (const float*)d_in[7];
    const float* n2g    = (const float*)d_in[8];
    const float* n2b    = (const float*)d_in[9];
    const float* w1     = (const float*)d_in[10];
    const float* b1     = (const float*)d_in[11];
    const float* w2     = (const float*)d_in[12];
    const float* b2     = (const float*)d_in[13];
    const int*   pidx   = (const int*)d_in[14];

    float* x   = (float*)d_out;
    u16* biasf = (u16*)d_ws;
    u16* wT    = biasf + (size_t)64 * 6 * LW * LW;
    u16* xnc   = wT + 884736;
    u16* qkvb  = xnc + (size_t)NTOK * C;
    u16* attnb = qkvb + (size_t)NTOK * 576;
    u16* hidb  = qkvb;                                   // NTOK*768 overlaps qkvb+attnb

    const size_t WBLK = 442368;
    const size_t OQKV = 0, OPROJ = 110592, OW1 = 147456, OW2 = 294912;

    hipMemcpyAsync(x, x_in, (size_t)NTOK * C * sizeof(float),
                   hipMemcpyDeviceToDevice, stream);

    for (int blk = 0; blk < 2; blk++) {
        u16* wb = wT + blk * WBLK;
        tconv_kernel<<<(576 * 192 + 255) / 256, 256, 0, stream>>>(
            qkv_w + (size_t)blk * C * 576, wb + OQKV, C, 576);
        tconv_kernel<<<(192 * 192 + 255) / 256, 256, 0, stream>>>(
            proj_w + (size_t)blk * C * C, wb + OPROJ, C, 192);
        tconv_kernel<<<(768 * 192 + 255) / 256, 256, 0, stream>>>(
            w1 + (size_t)blk * C * 768, wb + OW1, C, 768);
        tconv_kernel<<<(192 * 768 + 255) / 256, 256, 0, stream>>>(
            w2 + (size_t)blk * 768 * C, wb + OW2, 768, 192);
    }

    for (int blk = 0; blk < 2; blk++) {
        int roll = blk & 1;
        u16* wb = wT + blk * WBLK;
        biasmat_kernel<<<dim3(64, 6), 256, 0, stream>>>(
            btab + (size_t)blk * NPOS * 64 * 6, pidx, biasf);
        ln_kernel<<<NTOK / 4, 256, 0, stream>>>(
            x, n1g + blk * C, n1b + blk * C, xnc, 0, 1, roll);
        mm_kernel<0><<<dim3(9, NTOK / 128), 256, 0, stream>>>(
            xnc, wb + OQKV, qkv_b + blk * 576, qkvb, 576, C, 0, roll);
        if (roll)
            attn_kernel<1><<<NWIN, 384, 0, stream>>>(qkvb, biasf, attnb);
        else
            attn_kernel<0><<<NWIN, 384, 0, stream>>>(qkvb, biasf, attnb);
        mm_kernel<1><<<dim3(3, NTOK / 128), 256, 0, stream>>>(
            attnb, wb + OPROJ, proj_b + blk * C, x, 192, C, 0, roll);
        ln_kernel<<<NTOK / 4, 256, 0, stream>>>(
            x, n2g + blk * C, n2b + blk * C, xnc, 0, 0, 0);
        mm_kernel<2><<<dim3(12, NTOK / 128), 256, 0, stream>>>(
            xnc, wb + OW1, b1 + blk * 768, hidb, 768, C, 0, 0);
        mm_kernel<3><<<dim3(3, NTOK / 128), 256, 0, stream>>>(
            hidb, wb + OW2, b2 + blk * C, x, 192, 768, 0, 0);
    }
}